// Round 16
// baseline (127.891 us; speedup 1.0000x reference)
//
#include <hip/hip_runtime.h>
#include <hip/hip_bf16.h>
#include <stdint.h>
#include <stddef.h>

// ClusterLayer: q = normalize_rows( 1 / (1 + ||z-c||^2) )
// N=200000 rows, D=256, KC=256 clusters. fp32 in/out; cross-term via bf16 MFMA.
// R15 = R12's structure (best: 98.6us; pair-of-waves per unit, LDS-resident
// fragment-ordered B, raw s_barrier w/o vmcnt drain, tail-balanced sweeps)
// with MFMA shape 16x16x32 -> 32x32x16: per output row this HALVES the LDS
// B-read traffic (largest non-HBM pipe term: 6.1k cyc/CU-iter) and the MFMA
// count. Unit = 32 rows; each wave does 128 cols via acc[4] x f32x16 pinned
// to AGPRs with R14's proven "+a" inline asm (arch-VGPR side stays ~70).
// Layouts (verified family): A row=lane&31,k=(lane>>5)*8+e; B col=lane&31;
// C/D col=lane&31, row=(reg&3)+8*(reg>>2)+4*(lane>>5).

#define NT 512
#define GRID 256
#define UNITS (GRID * 4)   // 32-row units per sweep = 1024
#define D 256
#define KC 256

typedef __attribute__((ext_vector_type(8))) short short8;    // 8 bf16 (4 VGPRs)
typedef __attribute__((ext_vector_type(16))) float f32x16;   // 32x32 MFMA accumulator

// fp32 -> bf16, round-to-nearest-even (branch-free) — prep kernels only
__device__ __forceinline__ short f2bf(float f) {
    uint32_t u = __builtin_bit_cast(uint32_t, f);
    u += 0x7FFFu + ((u >> 16) & 1u);
    return (short)(u >> 16);
}

// packed RNE f32x2 -> bf16x2 (emits v_cvt_pk_bf16_f32)
__device__ __forceinline__ unsigned int pk2(float a, float b) {
    __hip_bfloat162 h = __float22bfloat162_rn(make_float2(a, b));
    unsigned int r;
    __builtin_memcpy(&r, &h, 4);
    return r;
}

// csq[k] = ||c_k||^2 ; one wave per cluster row.
__global__ void prep_csq(const float* __restrict__ C, float* __restrict__ csq) {
    const int k = blockIdx.x;
    const int l = threadIdx.x;  // 0..63
    float4 v = *(const float4*)(C + k * D + l * 4);
    float s = v.x * v.x + v.y * v.y + v.z * v.z + v.w * v.w;
#pragma unroll
    for (int off = 32; off > 0; off >>= 1) s += __shfl_down(s, off);
    if (l == 0) csq[k] = s;
}

// Reorder C into 32x32x16 MFMA-B fragment order, bf16:
// block (ks,cg), ks=0..15 (K=16 steps), cg=0..7 (32-col groups).
// Bf[((ks*8+cg)*64 + lane)*8 + e] = bf16( C[(cg*32 + (lane&31))*D + ks*16 + (lane>>5)*8 + e] )
// (B[k][col] = C[col][k]; lane holds col=lane&31, k=(lane>>5)*8+e)
__global__ void prep_reorder(const float* __restrict__ C, unsigned short* __restrict__ Bf) {
    const int ks = blockIdx.x >> 3;   // 0..15
    const int cg = blockIdx.x & 7;    // 0..7
    const int lane = threadIdx.x;     // 0..63
    const float* src = C + (size_t)(cg * 32 + (lane & 31)) * D + ks * 16 + (lane >> 5) * 8;
    float4 a0 = *(const float4*)(src);
    float4 a1 = *(const float4*)(src + 4);
    ushort4 p0, p1;
    p0.x = (unsigned short)f2bf(a0.x); p0.y = (unsigned short)f2bf(a0.y);
    p0.z = (unsigned short)f2bf(a0.z); p0.w = (unsigned short)f2bf(a0.w);
    p1.x = (unsigned short)f2bf(a1.x); p1.y = (unsigned short)f2bf(a1.y);
    p1.z = (unsigned short)f2bf(a1.z); p1.w = (unsigned short)f2bf(a1.w);
    unsigned short* dst = Bf + ((size_t)(ks * 8 + cg) * 64 + lane) * 8;
    *(ushort4*)(dst) = p0;
    *(ushort4*)(dst + 4) = p1;
}

__global__ void __launch_bounds__(NT)
main_kernel(const float* __restrict__ z,
            const uint4* __restrict__ Bf,
            const float* __restrict__ csq,
            float* __restrict__ out, int nunits) {
    __shared__ uint4 ldsB[8192];                       // 128KB fragment-ordered bf16 B
    __shared__ __align__(16) float ldsRS[2][8][2][16]; // [parity][wave][khalf][reg]

    const int tid  = threadIdx.x;
    const int lane = tid & 63;
    const int wave = tid >> 6;           // 0..7
    const int l31  = lane & 31;
    const int h    = lane >> 5;          // 0..1 (k-half / row-offset group)
    const int half = wave & 1;           // which 128-col half of the unit
    const int pair = wave >> 1;          // unit index within block (0..3)

    // stage whole B once (16 x dwordx4 per thread), linear -> conflict-free
#pragma unroll
    for (int i = 0; i < 16; ++i) ldsB[tid + i * NT] = Bf[tid + i * NT];
    __syncthreads();

    // c_sq for this lane's 4 col-groups (col = half*128 + cg*32 + l31)
    float csqr[4];
#pragma unroll
    for (int cg = 0; cg < 4; ++cg) csqr[cg] = csq[half * 128 + cg * 32 + l31];

    const char* ldsb = (const char*)ldsB;
    // byte addr = (ks<<13) + (cg<<10) + laneoff; laneoff folds half's cg-offset
    const int laneoff = (lane << 4) + (half << 12);

    // per-block iteration count (tail-balanced)
    const int niter = (nunits - blockIdx.x * 4 + UNITS - 1) / UNITS;

    int u = blockIdx.x * 4 + pair;                   // < 1024 <= nunits: initially valid

    // lane reads z[u*32 + l31][ks*16 + h*8 .. +8]
    const float* zrow = z + ((size_t)u * 32 + l31) * D + h * 8;
    // 2-deep rolling A ring across the 16 k-steps (and across units)
    float4 c0 = *(const float4*)(zrow),      c1 = *(const float4*)(zrow + 4);
    float4 d0 = *(const float4*)(zrow + 16), d1 = *(const float4*)(zrow + 20);

    for (int i = 0; i < niter; ++i) {
        const bool active = u < nunits;
        const int un = u + UNITS;
        const int unc = (un < nunits) ? un : (nunits - 1);
        const float* zrow_n = z + ((size_t)unc * 32 + l31) * D + h * 8;

        f32x16 acc[4];
#pragma unroll
        for (int cg = 0; cg < 4; ++cg) {
#pragma unroll
            for (int r = 0; r < 16; ++r) acc[cg][r] = 0.f;
        }
        float zsq_part = 0.f;

#pragma unroll
        for (int ks = 0; ks < 16; ++ks) {
            // prefetch 2 k-steps ahead; ks=14,15 fetch NEXT unit's k-steps 0,1
            const float* pf = (ks < 14) ? (zrow + (ks + 2) * 16) : (zrow_n + (ks - 14) * 16);
            float4 e0 = *(const float4*)(pf);
            float4 e1 = *(const float4*)(pf + 4);

            zsq_part += c0.x * c0.x + c0.y * c0.y + c0.z * c0.z + c0.w * c0.w +
                        c1.x * c1.x + c1.y * c1.y + c1.z * c1.z + c1.w * c1.w;
            // packed RNE conversion: 4x v_cvt_pk_bf16_f32
            uint4 uu;
            uu.x = pk2(c0.x, c0.y); uu.y = pk2(c0.z, c0.w);
            uu.z = pk2(c1.x, c1.y); uu.w = pk2(c1.z, c1.w);
            short8 af;
            __builtin_memcpy(&af, &uu, 16);
#pragma unroll
            for (int cg = 0; cg < 4; ++cg) {
                // linear per-lane address -> zero bank conflicts
                short8 bf = *(const short8*)(ldsb + laneoff + (ks << 13) + (cg << 10));
                asm("v_mfma_f32_32x32x16_bf16 %0, %1, %2, %0"
                    : "+a"(acc[cg])
                    : "v"(af), "v"(bf));
            }
            c0 = d0; c1 = d1; d0 = e0; d1 = e1;
        }
        // ring now holds next unit's k-steps 0,1 (loads may still be in flight)

        // ||z_row||^2: lane has row l31's partial over k-half h; combine halves
        float zsq = zsq_part;
        zsq += __shfl_xor(zsq, 32);      // lanes 0..31 now hold full zsq[row l31]
        // redistribute to C/D rows: row(reg) = (reg&3) + 8*(reg>>2) + 4*h
        float zsqj[16];
#pragma unroll
        for (int r = 0; r < 16; ++r) zsqj[r] = __shfl(zsq, (r & 3) + 8 * (r >> 2) + 4 * h);

        // q = 1/(1+dist); per-lane partial row sums (over this wave's 128 cols)
        float rs[16];
#pragma unroll
        for (int r = 0; r < 16; ++r) rs[r] = 0.f;
#pragma unroll
        for (int cg = 0; cg < 4; ++cg) {
#pragma unroll
            for (int r = 0; r < 16; ++r) {
                float dist = zsqj[r] + csqr[cg] - 2.0f * acc[cg][r];
                dist = fmaxf(dist, 0.f);
                float qv = 1.0f / (1.0f + dist);
                acc[cg][r] = qv;
                rs[r] += qv;
            }
        }
        // reduce over the 32 lanes of this k-half (all hold same rows)
#pragma unroll
        for (int r = 0; r < 16; ++r) {
            float s = rs[r];
            s += __shfl_xor(s, 1);
            s += __shfl_xor(s, 2);
            s += __shfl_xor(s, 4);
            s += __shfl_xor(s, 8);
            s += __shfl_xor(s, 16);
            rs[r] = s;
        }
        // exchange with partner wave (other 128 cols), parity double-buffered.
        // partner's reg r maps to the same row (same h-group) -> index by (h,reg).
        if (l31 == 0) {
#pragma unroll
            for (int r = 0; r < 16; ++r) ldsRS[i & 1][wave][h][r] = rs[r];
        }
        asm volatile("s_waitcnt lgkmcnt(0)" ::: "memory");
        __builtin_amdgcn_s_barrier();          // raw: vmcnt NOT drained
        __builtin_amdgcn_sched_barrier(0);
        float inv[16];
#pragma unroll
        for (int r = 0; r < 16; ++r)
            inv[r] = 1.0f / (rs[r] + ldsRS[i & 1][wave ^ 1][h][r]);

        if (active) {
#pragma unroll
            for (int r = 0; r < 16; ++r) {
                float* orow = out + ((size_t)u * 32 + (r & 3) + 8 * (r >> 2) + 4 * h) * KC
                              + half * 128 + l31;
#pragma unroll
                for (int cg = 0; cg < 4; ++cg) orow[cg * 32] = acc[cg][r] * inv[r];
            }
        }
        u = un;
        zrow = zrow_n;
    }
}

extern "C" void kernel_launch(void* const* d_in, const int* in_sizes, int n_in,
                              void* d_out, int out_size, void* d_ws, size_t ws_size,
                              hipStream_t stream) {
    const float* zp = (const float*)d_in[0];
    const float* Cp = (const float*)d_in[1];
    const int N = in_sizes[0] / D;  // 200000
    unsigned short* Bf = (unsigned short*)d_ws;                          // 128KB bf16 frag-ordered
    float* csq = (float*)((char*)d_ws + (size_t)KC * D * sizeof(unsigned short));  // 1KB

    prep_csq<<<KC, 64, 0, stream>>>(Cp, csq);
    prep_reorder<<<128, 64, 0, stream>>>(Cp, Bf);

    const int nunits = N / 32;  // 6250 (N divisible by 32)
    main_kernel<<<GRID, NT, 0, stream>>>(zp, (const uint4*)Bf, csq, (float*)d_out, nunits);
}

// Round 17
// 119.018 us; speedup vs baseline: 1.0746x; 1.0746x over previous
//
#include <hip/hip_runtime.h>
#include <hip/hip_bf16.h>
#include <stdint.h>
#include <stddef.h>

// ClusterLayer: q = normalize_rows( 1 / (1 + ||z-c||^2) )
// N=200000 rows, D=256, KC=256 clusters. fp32 in/out; cross-term via bf16 MFMA.
// R16 = R10 (2 tiles per wave-pair: one ds_read_b128 feeds TWO MFMAs, half the
// LDS traffic and half the barriers per row vs R12) + R14's proven "+a" AGPR
// pinning for accA/accB (64 AGPRs). R10's regression was allocator choke at
// the 128-VGPR cap (acc in arch VGPRs); with acc pinned to AGPRs the arch side
// is ~70 regs -> scheduler freedom restored. Epilogue per-row identical to R12
// (R15 showed the 32x32 shape's epilogue bloat eats its LDS win).

#define NT 512
#define GRID 256
#define UNITS (GRID * 4)   // wave-pair units per sweep = 1024 (each = 2 tiles)
#define D 256
#define KC 256

typedef __attribute__((ext_vector_type(8))) short short8;  // 8 bf16 (4 VGPRs)
typedef __attribute__((ext_vector_type(4))) float f32x4;   // MFMA accumulator

// fp32 -> bf16, round-to-nearest-even (branch-free) — prep kernels only
__device__ __forceinline__ short f2bf(float f) {
    uint32_t u = __builtin_bit_cast(uint32_t, f);
    u += 0x7FFFu + ((u >> 16) & 1u);
    return (short)(u >> 16);
}

// packed RNE f32x2 -> bf16x2 (emits v_cvt_pk_bf16_f32)
__device__ __forceinline__ unsigned int pk2(float a, float b) {
    __hip_bfloat162 h = __float22bfloat162_rn(make_float2(a, b));
    unsigned int r;
    __builtin_memcpy(&r, &h, 4);
    return r;
}

// csq[k] = ||c_k||^2 ; one wave per cluster row.
__global__ void prep_csq(const float* __restrict__ C, float* __restrict__ csq) {
    const int k = blockIdx.x;
    const int l = threadIdx.x;  // 0..63
    float4 v = *(const float4*)(C + k * D + l * 4);
    float s = v.x * v.x + v.y * v.y + v.z * v.z + v.w * v.w;
#pragma unroll
    for (int off = 32; off > 0; off >>= 1) s += __shfl_down(s, off);
    if (l == 0) csq[k] = s;
}

// Reorder C into MFMA-B fragment order, bf16 (verified R1-R14):
// Bf[((kk*16 + ct)*64 + lane)*8 + e] = bf16( C[(ct*16 + (lane&15))*D + kk*32 + (lane>>4)*8 + e] )
__global__ void prep_reorder(const float* __restrict__ C, unsigned short* __restrict__ Bf) {
    const int kk = blockIdx.x >> 4;   // 0..7
    const int ct = blockIdx.x & 15;   // 0..15
    const int lane = threadIdx.x;     // 0..63
    const int l15 = lane & 15;
    const int lg = lane >> 4;
    const float* src = C + (size_t)(ct * 16 + l15) * D + kk * 32 + lg * 8;
    float4 a0 = *(const float4*)(src);
    float4 a1 = *(const float4*)(src + 4);
    ushort4 p0, p1;
    p0.x = (unsigned short)f2bf(a0.x); p0.y = (unsigned short)f2bf(a0.y);
    p0.z = (unsigned short)f2bf(a0.z); p0.w = (unsigned short)f2bf(a0.w);
    p1.x = (unsigned short)f2bf(a1.x); p1.y = (unsigned short)f2bf(a1.y);
    p1.z = (unsigned short)f2bf(a1.z); p1.w = (unsigned short)f2bf(a1.w);
    unsigned short* dst = Bf + ((size_t)(kk * 16 + ct) * 64 + lane) * 8;
    *(ushort4*)(dst) = p0;
    *(ushort4*)(dst + 4) = p1;
}

__global__ void __launch_bounds__(NT)
main_kernel(const float* __restrict__ z,
            const uint4* __restrict__ Bf,
            const float* __restrict__ csq,
            float* __restrict__ out, int ntiles) {
    __shared__ uint4 ldsB[8192];                        // 128KB fragment-ordered bf16 B
    __shared__ __align__(16) float ldsRS[2][8][2][16];  // [parity][wave][tile][row]

    const int tid  = threadIdx.x;
    const int lane = tid & 63;
    const int wave = tid >> 6;           // 0..7
    const int l15  = lane & 15;
    const int lg   = lane >> 4;          // 0..3
    const int half = wave & 1;           // which 128-col half of the tiles
    const int pair = wave >> 1;          // unit index within block (0..3)

    // stage whole B once (16 x dwordx4 per thread), linear -> conflict-free
#pragma unroll
    for (int i = 0; i < 16; ++i) ldsB[tid + i * NT] = Bf[tid + i * NT];
    __syncthreads();

    // c_sq for this lane's 8 columns (col = half*128 + ct*16 + l15)
    float csqr[8];
#pragma unroll
    for (int ct = 0; ct < 8; ++ct) csqr[ct] = csq[half * 128 + ct * 16 + l15];

    const char* ldsb = (const char*)ldsB;
    const int laneoff = (lane << 4) + (half << 13);  // lane*16 + half*8 frag-blocks

    const int nunits = ntiles >> 1;                  // 6250 (ntiles even)
    // per-block iteration count (tail-balanced)
    const int niter = (nunits - blockIdx.x * 4 + UNITS - 1) / UNITS;

    int u = blockIdx.x * 4 + pair;                   // < 1024 <= nunits: initially valid

    // unit u owns rows [u*32, u*32+32): tile a = rows u*32+l15, tile b = +16
    const float* zrow_a = z + ((size_t)u * 32 + l15) * D + lg * 8;
    const float* zrow_b = zrow_a + 16 * D;
    // 2-deep rolling ring per tile: slot kk&1 holds k-step kk; refill with kk+2.
    float4 Sa0[2], Sa1[2], Sb0[2], Sb1[2];
#pragma unroll
    for (int s = 0; s < 2; ++s) {
        Sa0[s] = *(const float4*)(zrow_a + s * 32);
        Sa1[s] = *(const float4*)(zrow_a + s * 32 + 4);
        Sb0[s] = *(const float4*)(zrow_b + s * 32);
        Sb1[s] = *(const float4*)(zrow_b + s * 32 + 4);
    }

    for (int i = 0; i < niter; ++i) {
        const bool active = u < nunits;
        const int un = u + UNITS;
        const int unc = (un < nunits) ? un : (nunits - 1);
        const float* zrow_na = z + ((size_t)unc * 32 + l15) * D + lg * 8;
        const float* zrow_nb = zrow_na + 16 * D;

        // acc pinned to AGPRs via "+a" asm (2 x 32 = 64 AGPRs)
        f32x4 accA[8], accB[8];
        const f32x4 zero4 = {0.f, 0.f, 0.f, 0.f};
#pragma unroll
        for (int ct = 0; ct < 8; ++ct) { accA[ct] = zero4; accB[ct] = zero4; }
        float zsq_a = 0.f, zsq_b = 0.f;

#pragma unroll
        for (int kk = 0; kk < 8; ++kk) {
            // consume ring slot kk&1, refill with k-step kk+2
            // (kk>=6 refills from the NEXT unit's k-steps 0,1)
            float4 ca0 = Sa0[kk & 1], ca1 = Sa1[kk & 1];
            float4 cb0 = Sb0[kk & 1], cb1 = Sb1[kk & 1];
            const float* pfa = (kk < 6) ? (zrow_a + (kk + 2) * 32) : (zrow_na + (kk - 6) * 32);
            const float* pfb = (kk < 6) ? (zrow_b + (kk + 2) * 32) : (zrow_nb + (kk - 6) * 32);
            Sa0[kk & 1] = *(const float4*)(pfa);
            Sa1[kk & 1] = *(const float4*)(pfa + 4);
            Sb0[kk & 1] = *(const float4*)(pfb);
            Sb1[kk & 1] = *(const float4*)(pfb + 4);

            zsq_a += ca0.x * ca0.x + ca0.y * ca0.y + ca0.z * ca0.z + ca0.w * ca0.w +
                     ca1.x * ca1.x + ca1.y * ca1.y + ca1.z * ca1.z + ca1.w * ca1.w;
            zsq_b += cb0.x * cb0.x + cb0.y * cb0.y + cb0.z * cb0.z + cb0.w * cb0.w +
                     cb1.x * cb1.x + cb1.y * cb1.y + cb1.z * cb1.z + cb1.w * cb1.w;
            // packed RNE conversion: v_cvt_pk_bf16_f32
            uint4 ua, ub;
            ua.x = pk2(ca0.x, ca0.y); ua.y = pk2(ca0.z, ca0.w);
            ua.z = pk2(ca1.x, ca1.y); ua.w = pk2(ca1.z, ca1.w);
            ub.x = pk2(cb0.x, cb0.y); ub.y = pk2(cb0.z, cb0.w);
            ub.z = pk2(cb1.x, cb1.y); ub.w = pk2(cb1.z, cb1.w);
            short8 afa, afb;
            __builtin_memcpy(&afa, &ua, 16);
            __builtin_memcpy(&afb, &ub, 16);
#pragma unroll
            for (int ct = 0; ct < 8; ++ct) {
                // one linear conflict-free ds_read feeds BOTH tiles' MFMAs
                short8 bf = *(const short8*)(ldsb + laneoff + ((kk * 16 + ct) << 10));
                asm("v_mfma_f32_16x16x32_bf16 %0, %1, %2, %0"
                    : "+a"(accA[ct]) : "v"(afa), "v"(bf));
                asm("v_mfma_f32_16x16x32_bf16 %0, %1, %2, %0"
                    : "+a"(accB[ct]) : "v"(afb), "v"(bf));
            }
        }
        // ring now holds next unit's k-steps 0,1 (loads may still be in flight)

        // ||z_row||^2 per tile: lane holds partial for row l15; sum lane-groups
        float zsqj_a[4], zsqj_b[4];
        {
            float za = zsq_a;
            za += __shfl_xor(za, 16);
            za += __shfl_xor(za, 32);
            float zb = zsq_b;
            zb += __shfl_xor(zb, 16);
            zb += __shfl_xor(zb, 32);
#pragma unroll
            for (int j = 0; j < 4; ++j) {
                zsqj_a[j] = __shfl(za, lg * 4 + j);
                zsqj_b[j] = __shfl(zb, lg * 4 + j);
            }
        }

        // q = 1/(1+dist); per-lane partial row sums over this wave's 8 col-frags
        float rsA[4] = {0.f, 0.f, 0.f, 0.f}, rsB[4] = {0.f, 0.f, 0.f, 0.f};
#pragma unroll
        for (int ct = 0; ct < 8; ++ct) {
#pragma unroll
            for (int j = 0; j < 4; ++j) {
                float da = zsqj_a[j] + csqr[ct] - 2.0f * accA[ct][j];
                float db = zsqj_b[j] + csqr[ct] - 2.0f * accB[ct][j];
                da = fmaxf(da, 0.f);
                db = fmaxf(db, 0.f);
                float qa = 1.0f / (1.0f + da);
                float qb = 1.0f / (1.0f + db);
                accA[ct][j] = qa; rsA[j] += qa;
                accB[ct][j] = qb; rsB[j] += qb;
            }
        }
        // reduce over the 16-lane column group -> this wave's 128-col row sums
#pragma unroll
        for (int j = 0; j < 4; ++j) {
            float sa = rsA[j], sb = rsB[j];
            sa += __shfl_xor(sa, 1); sb += __shfl_xor(sb, 1);
            sa += __shfl_xor(sa, 2); sb += __shfl_xor(sb, 2);
            sa += __shfl_xor(sa, 4); sb += __shfl_xor(sb, 4);
            sa += __shfl_xor(sa, 8); sb += __shfl_xor(sb, 8);
            rsA[j] = sa; rsB[j] = sb;
        }
        // exchange with partner wave (other 128 cols), parity double-buffered
        if (l15 == 0) {
            float4 wa = {rsA[0], rsA[1], rsA[2], rsA[3]};
            float4 wb = {rsB[0], rsB[1], rsB[2], rsB[3]};
            *(float4*)&ldsRS[i & 1][wave][0][lg * 4] = wa;
            *(float4*)&ldsRS[i & 1][wave][1][lg * 4] = wb;
        }
        asm volatile("s_waitcnt lgkmcnt(0)" ::: "memory");
        __builtin_amdgcn_s_barrier();          // raw: vmcnt NOT drained
        __builtin_amdgcn_sched_barrier(0);
        float4 pa = *(const float4*)&ldsRS[i & 1][wave ^ 1][0][lg * 4];
        float4 pb = *(const float4*)&ldsRS[i & 1][wave ^ 1][1][lg * 4];
        float invA[4], invB[4];
        invA[0] = 1.0f / (rsA[0] + pa.x); invB[0] = 1.0f / (rsB[0] + pb.x);
        invA[1] = 1.0f / (rsA[1] + pa.y); invB[1] = 1.0f / (rsB[1] + pb.y);
        invA[2] = 1.0f / (rsA[2] + pa.z); invB[2] = 1.0f / (rsB[2] + pb.z);
        invA[3] = 1.0f / (rsA[3] + pa.w); invB[3] = 1.0f / (rsB[3] + pb.w);

        if (active) {
#pragma unroll
            for (int j = 0; j < 4; ++j) {
                float* orow = out + ((size_t)u * 32 + lg * 4 + j) * KC + half * 128 + l15;
#pragma unroll
                for (int ct = 0; ct < 8; ++ct) {
                    orow[ct * 16] = accA[ct][j] * invA[j];
                    orow[16 * KC + ct * 16] = accB[ct][j] * invB[j];
                }
            }
        }
        u = un;
        zrow_a = zrow_na;
        zrow_b = zrow_nb;
    }
}

extern "C" void kernel_launch(void* const* d_in, const int* in_sizes, int n_in,
                              void* d_out, int out_size, void* d_ws, size_t ws_size,
                              hipStream_t stream) {
    const float* zp = (const float*)d_in[0];
    const float* Cp = (const float*)d_in[1];
    const int N = in_sizes[0] / D;  // 200000
    unsigned short* Bf = (unsigned short*)d_ws;                          // 128KB bf16 frag-ordered
    float* csq = (float*)((char*)d_ws + (size_t)KC * D * sizeof(unsigned short));  // 1KB

    prep_csq<<<KC, 64, 0, stream>>>(Cp, csq);
    prep_reorder<<<128, 64, 0, stream>>>(Cp, Bf);

    const int ntiles = (N + 15) / 16;  // 12500
    main_kernel<<<GRID, NT, 0, stream>>>(zp, (const uint4*)Bf, csq, (float*)d_out, ntiles);
}

// Round 18
// 96.068 us; speedup vs baseline: 1.3313x; 1.2389x over previous
//
#include <hip/hip_runtime.h>
#include <hip/hip_bf16.h>
#include <stdint.h>
#include <stddef.h>

// ClusterLayer: q = normalize_rows( 1 / (1 + ||z-c||^2) )
// N=200000 rows, D=256, KC=256 clusters. fp32 in/out; cross-term via bf16 MFMA.
// R17 = R12 (best: 98.6us; pair-of-waves per 16-row tile, LDS-resident
// fragment-ordered B, 8-deep cross-tile A ring, raw s_barrier w/o vmcnt drain)
// + v_rcp_f32 via __builtin_amdgcn_rcpf for ALL divides in the main kernel.
// Without fast-math, hipcc expands each 1.0f/x into the ~10-op IEEE div
// sequence; 64 q-divides + 4 row-inversions per wave-iter = ~1300 VALU cycles
// (VALUBusy 33% with only ~2-3k of necessary work -> divide expansion is the
// largest removable term). rcp is 1-ulp: q~4e-3 -> err ~1e-9 << 8.2e-5 thr.

#define NT 512
#define GRID 256
#define PAIRS (GRID * 4)   // tile-pairs per sweep = 1024
#define D 256
#define KC 256

typedef __attribute__((ext_vector_type(8))) short short8;  // 8 bf16 (4 VGPRs)
typedef __attribute__((ext_vector_type(4))) float f32x4;   // MFMA accumulator

// fast 1-ulp reciprocal (single v_rcp_f32)
__device__ __forceinline__ float frcp(float x) { return __builtin_amdgcn_rcpf(x); }

// fp32 -> bf16, round-to-nearest-even (branch-free) — prep kernels only
__device__ __forceinline__ short f2bf(float f) {
    uint32_t u = __builtin_bit_cast(uint32_t, f);
    u += 0x7FFFu + ((u >> 16) & 1u);
    return (short)(u >> 16);
}

// packed RNE f32x2 -> bf16x2 (emits v_cvt_pk_bf16_f32)
__device__ __forceinline__ unsigned int pk2(float a, float b) {
    __hip_bfloat162 h = __float22bfloat162_rn(make_float2(a, b));
    unsigned int r;
    __builtin_memcpy(&r, &h, 4);
    return r;
}

// csq[k] = ||c_k||^2 ; one wave per cluster row.
__global__ void prep_csq(const float* __restrict__ C, float* __restrict__ csq) {
    const int k = blockIdx.x;
    const int l = threadIdx.x;  // 0..63
    float4 v = *(const float4*)(C + k * D + l * 4);
    float s = v.x * v.x + v.y * v.y + v.z * v.z + v.w * v.w;
#pragma unroll
    for (int off = 32; off > 0; off >>= 1) s += __shfl_down(s, off);
    if (l == 0) csq[k] = s;
}

// Reorder C into MFMA-B fragment order, bf16 (verified R1-R16):
// Bf[((kk*16 + ct)*64 + lane)*8 + e] = bf16( C[(ct*16 + (lane&15))*D + kk*32 + (lane>>4)*8 + e] )
__global__ void prep_reorder(const float* __restrict__ C, unsigned short* __restrict__ Bf) {
    const int kk = blockIdx.x >> 4;   // 0..7
    const int ct = blockIdx.x & 15;   // 0..15
    const int lane = threadIdx.x;     // 0..63
    const int l15 = lane & 15;
    const int lg = lane >> 4;
    const float* src = C + (size_t)(ct * 16 + l15) * D + kk * 32 + lg * 8;
    float4 a0 = *(const float4*)(src);
    float4 a1 = *(const float4*)(src + 4);
    ushort4 p0, p1;
    p0.x = (unsigned short)f2bf(a0.x); p0.y = (unsigned short)f2bf(a0.y);
    p0.z = (unsigned short)f2bf(a0.z); p0.w = (unsigned short)f2bf(a0.w);
    p1.x = (unsigned short)f2bf(a1.x); p1.y = (unsigned short)f2bf(a1.y);
    p1.z = (unsigned short)f2bf(a1.z); p1.w = (unsigned short)f2bf(a1.w);
    unsigned short* dst = Bf + ((size_t)(kk * 16 + ct) * 64 + lane) * 8;
    *(ushort4*)(dst) = p0;
    *(ushort4*)(dst + 4) = p1;
}

__global__ void __launch_bounds__(NT)
main_kernel(const float* __restrict__ z,
            const uint4* __restrict__ Bf,
            const float* __restrict__ csq,
            float* __restrict__ out, int ntiles) {
    __shared__ uint4 ldsB[8192];                       // 128KB fragment-ordered bf16 B
    __shared__ __align__(16) float ldsRS[2][8][16];    // [parity][wave][row] row-sum exchange

    const int tid  = threadIdx.x;
    const int lane = tid & 63;
    const int wave = tid >> 6;           // 0..7
    const int l15  = lane & 15;
    const int lg   = lane >> 4;          // 0..3
    const int half = wave & 1;           // which 128-col half of the tile
    const int pair = wave >> 1;          // tile-pair index within block (0..3)

    // stage whole B once (16 x dwordx4 per thread), linear -> conflict-free
#pragma unroll
    for (int i = 0; i < 16; ++i) ldsB[tid + i * NT] = Bf[tid + i * NT];
    __syncthreads();

    // c_sq for this lane's 8 columns (col = half*128 + ct*16 + l15)
    float csqr[8];
#pragma unroll
    for (int ct = 0; ct < 8; ++ct) csqr[ct] = csq[half * 128 + ct * 16 + l15];

    const char* ldsb = (const char*)ldsB;
    const int laneoff = (lane << 4) + (half << 13);  // lane*16 + half*8 frag-blocks

    // per-block iteration count (tail-balanced)
    const int niter = (ntiles - blockIdx.x * 4 + PAIRS - 1) / PAIRS;

    int t = blockIdx.x * 4 + pair;                   // < 1024 <= ntiles: initially valid

    const float* zrow = z + (size_t)(t * 16 + l15) * D + lg * 8;
    // 8-deep rolling A ring: S[kk] holds k-step kk of the current tile;
    // consuming S[kk] refills it with the NEXT tile's k-step kk.
    float4 S0[8], S1[8];
#pragma unroll
    for (int s = 0; s < 8; ++s) {
        S0[s] = *(const float4*)(zrow + s * 32);
        S1[s] = *(const float4*)(zrow + s * 32 + 4);
    }

    for (int i = 0; i < niter; ++i) {
        const bool active = t < ntiles;
        const int tn = t + PAIRS;
        const int tnc = (tn < ntiles) ? tn : (ntiles - 1);
        const float* zrow_n = z + (size_t)(tnc * 16 + l15) * D + lg * 8;

        f32x4 acc[8];
        const f32x4 zero4 = {0.f, 0.f, 0.f, 0.f};
#pragma unroll
        for (int ct = 0; ct < 8; ++ct) acc[ct] = zero4;
        float zsq_part = 0.f;

#pragma unroll
        for (int kk = 0; kk < 8; ++kk) {
            // consume slot kk (loaded one full tile ago), refill with next tile
            float4 c0 = S0[kk], c1 = S1[kk];
            const float* pf = zrow_n + kk * 32;
            S0[kk] = *(const float4*)(pf);
            S1[kk] = *(const float4*)(pf + 4);

            zsq_part += c0.x * c0.x + c0.y * c0.y + c0.z * c0.z + c0.w * c0.w +
                        c1.x * c1.x + c1.y * c1.y + c1.z * c1.z + c1.w * c1.w;
            // packed RNE conversion: 4x v_cvt_pk_bf16_f32
            uint4 u;
            u.x = pk2(c0.x, c0.y); u.y = pk2(c0.z, c0.w);
            u.z = pk2(c1.x, c1.y); u.w = pk2(c1.z, c1.w);
            short8 af;
            __builtin_memcpy(&af, &u, 16);
#pragma unroll
            for (int ct = 0; ct < 8; ++ct) {
                // linear per-lane address -> zero bank conflicts
                short8 bf = *(const short8*)(ldsb + laneoff + ((kk * 16 + ct) << 10));
                acc[ct] = __builtin_amdgcn_mfma_f32_16x16x32_bf16(af, bf, acc[ct], 0, 0, 0);
            }
        }
        // ring now holds next tile's k-steps 0..7 (loads may still be in flight)

        // ||z_row||^2: lane holds partial for row l15; sum over the 4 lane-groups
        float zsq = zsq_part;
        zsq += __shfl_xor(zsq, 16);
        zsq += __shfl_xor(zsq, 32);
        float zsqj[4];
#pragma unroll
        for (int j = 0; j < 4; ++j) zsqj[j] = __shfl(zsq, lg * 4 + j);

        // q = rcp(1+dist); per-lane partial row sums over this wave's 8 col-frags
        float rs[4] = {0.f, 0.f, 0.f, 0.f};
#pragma unroll
        for (int ct = 0; ct < 8; ++ct) {
#pragma unroll
            for (int j = 0; j < 4; ++j) {
                float dist = zsqj[j] + csqr[ct] - 2.0f * acc[ct][j];
                dist = fmaxf(dist, 0.f);
                float qv = frcp(1.0f + dist);        // single v_rcp_f32
                acc[ct][j] = qv;
                rs[j] += qv;
            }
        }
        // reduce over the 16-lane column group -> this wave's 128-col row sums
#pragma unroll
        for (int j = 0; j < 4; ++j) {
            float s = rs[j];
            s += __shfl_xor(s, 1);
            s += __shfl_xor(s, 2);
            s += __shfl_xor(s, 4);
            s += __shfl_xor(s, 8);
            rs[j] = s;
        }
        // exchange with partner wave (other 128 cols), parity double-buffered
        if (l15 == 0) {
            float4 w = {rs[0], rs[1], rs[2], rs[3]};
            *(float4*)&ldsRS[i & 1][wave][lg * 4] = w;
        }
        asm volatile("s_waitcnt lgkmcnt(0)" ::: "memory");
        __builtin_amdgcn_s_barrier();          // raw: vmcnt NOT drained
        __builtin_amdgcn_sched_barrier(0);
        float4 prs = *(const float4*)&ldsRS[i & 1][wave ^ 1][lg * 4];
        float inv[4];
        inv[0] = frcp(rs[0] + prs.x);
        inv[1] = frcp(rs[1] + prs.y);
        inv[2] = frcp(rs[2] + prs.z);
        inv[3] = frcp(rs[3] + prs.w);

        if (active) {
#pragma unroll
            for (int j = 0; j < 4; ++j) {
                float* orow = out + (size_t)(t * 16 + lg * 4 + j) * KC + half * 128 + l15;
#pragma unroll
                for (int ct = 0; ct < 8; ++ct) orow[ct * 16] = acc[ct][j] * inv[j];
            }
        }
        t = tn;
        zrow = zrow_n;
    }
}

extern "C" void kernel_launch(void* const* d_in, const int* in_sizes, int n_in,
                              void* d_out, int out_size, void* d_ws, size_t ws_size,
                              hipStream_t stream) {
    const float* zp = (const float*)d_in[0];
    const float* Cp = (const float*)d_in[1];
    const int N = in_sizes[0] / D;  // 200000
    unsigned short* Bf = (unsigned short*)d_ws;                          // 128KB bf16 frag-ordered
    float* csq = (float*)((char*)d_ws + (size_t)KC * D * sizeof(unsigned short));  // 1KB

    prep_csq<<<KC, 64, 0, stream>>>(Cp, csq);
    prep_reorder<<<128, 64, 0, stream>>>(Cp, Bf);

    const int ntiles = (N + 15) / 16;  // 12500
    main_kernel<<<GRID, NT, 0, stream>>>(zp, (const uint4*)Bf, csq, (float*)d_out, ntiles);
}

// Round 19
// 91.164 us; speedup vs baseline: 1.4029x; 1.0538x over previous
//
#include <hip/hip_runtime.h>
#include <hip/hip_bf16.h>
#include <stdint.h>
#include <stddef.h>

// ClusterLayer: q = normalize_rows( 1 / (1 + ||z-c||^2) )
// N=200000 rows, D=256, KC=256 clusters. fp32 in/out; cross-term via bf16 MFMA.
// R18 = R17 (96.1us: R12 structure + frcp) +
//  (a) NONTEMPORAL stores for out: out is write-once/never-read; normal stores
//      write-allocate in L2/L3 and evict the not-yet-read half of z (FETCH
//      measured 100MB = half of z missing to HBM). NT stores preserve z's L3
//      residency -> HBM read traffic drops.
//  (b) fold the "+1.0f" into csqr at load (clamp becomes fmaxf(.,1.0f)):
//      saves 32 v_add per wave-iter.

#define NT 512
#define GRID 256
#define PAIRS (GRID * 4)   // tile-pairs per sweep = 1024
#define D 256
#define KC 256

typedef __attribute__((ext_vector_type(8))) short short8;  // 8 bf16 (4 VGPRs)
typedef __attribute__((ext_vector_type(4))) float f32x4;   // MFMA accumulator

// fast 1-ulp reciprocal (single v_rcp_f32)
__device__ __forceinline__ float frcp(float x) { return __builtin_amdgcn_rcpf(x); }

// fp32 -> bf16, round-to-nearest-even (branch-free) — prep kernels only
__device__ __forceinline__ short f2bf(float f) {
    uint32_t u = __builtin_bit_cast(uint32_t, f);
    u += 0x7FFFu + ((u >> 16) & 1u);
    return (short)(u >> 16);
}

// packed RNE f32x2 -> bf16x2 (emits v_cvt_pk_bf16_f32)
__device__ __forceinline__ unsigned int pk2(float a, float b) {
    __hip_bfloat162 h = __float22bfloat162_rn(make_float2(a, b));
    unsigned int r;
    __builtin_memcpy(&r, &h, 4);
    return r;
}

// csq[k] = ||c_k||^2 ; one wave per cluster row.
__global__ void prep_csq(const float* __restrict__ C, float* __restrict__ csq) {
    const int k = blockIdx.x;
    const int l = threadIdx.x;  // 0..63
    float4 v = *(const float4*)(C + k * D + l * 4);
    float s = v.x * v.x + v.y * v.y + v.z * v.z + v.w * v.w;
#pragma unroll
    for (int off = 32; off > 0; off >>= 1) s += __shfl_down(s, off);
    if (l == 0) csq[k] = s;
}

// Reorder C into MFMA-B fragment order, bf16 (verified R1-R17):
// Bf[((kk*16 + ct)*64 + lane)*8 + e] = bf16( C[(ct*16 + (lane&15))*D + kk*32 + (lane>>4)*8 + e] )
__global__ void prep_reorder(const float* __restrict__ C, unsigned short* __restrict__ Bf) {
    const int kk = blockIdx.x >> 4;   // 0..7
    const int ct = blockIdx.x & 15;   // 0..15
    const int lane = threadIdx.x;     // 0..63
    const int l15 = lane & 15;
    const int lg = lane >> 4;
    const float* src = C + (size_t)(ct * 16 + l15) * D + kk * 32 + lg * 8;
    float4 a0 = *(const float4*)(src);
    float4 a1 = *(const float4*)(src + 4);
    ushort4 p0, p1;
    p0.x = (unsigned short)f2bf(a0.x); p0.y = (unsigned short)f2bf(a0.y);
    p0.z = (unsigned short)f2bf(a0.z); p0.w = (unsigned short)f2bf(a0.w);
    p1.x = (unsigned short)f2bf(a1.x); p1.y = (unsigned short)f2bf(a1.y);
    p1.z = (unsigned short)f2bf(a1.z); p1.w = (unsigned short)f2bf(a1.w);
    unsigned short* dst = Bf + ((size_t)(kk * 16 + ct) * 64 + lane) * 8;
    *(ushort4*)(dst) = p0;
    *(ushort4*)(dst + 4) = p1;
}

__global__ void __launch_bounds__(NT)
main_kernel(const float* __restrict__ z,
            const uint4* __restrict__ Bf,
            const float* __restrict__ csq,
            float* __restrict__ out, int ntiles) {
    __shared__ uint4 ldsB[8192];                       // 128KB fragment-ordered bf16 B
    __shared__ __align__(16) float ldsRS[2][8][16];    // [parity][wave][row] row-sum exchange

    const int tid  = threadIdx.x;
    const int lane = tid & 63;
    const int wave = tid >> 6;           // 0..7
    const int l15  = lane & 15;
    const int lg   = lane >> 4;          // 0..3
    const int half = wave & 1;           // which 128-col half of the tile
    const int pair = wave >> 1;          // tile-pair index within block (0..3)

    // stage whole B once (16 x dwordx4 per thread), linear -> conflict-free
#pragma unroll
    for (int i = 0; i < 16; ++i) ldsB[tid + i * NT] = Bf[tid + i * NT];
    __syncthreads();

    // 1 + c_sq for this lane's 8 columns (col = half*128 + ct*16 + l15)
    float csqr1[8];
#pragma unroll
    for (int ct = 0; ct < 8; ++ct) csqr1[ct] = 1.0f + csq[half * 128 + ct * 16 + l15];

    const char* ldsb = (const char*)ldsB;
    const int laneoff = (lane << 4) + (half << 13);  // lane*16 + half*8 frag-blocks

    // per-block iteration count (tail-balanced)
    const int niter = (ntiles - blockIdx.x * 4 + PAIRS - 1) / PAIRS;

    int t = blockIdx.x * 4 + pair;                   // < 1024 <= ntiles: initially valid

    const float* zrow = z + (size_t)(t * 16 + l15) * D + lg * 8;
    // 8-deep rolling A ring: S[kk] holds k-step kk of the current tile;
    // consuming S[kk] refills it with the NEXT tile's k-step kk.
    float4 S0[8], S1[8];
#pragma unroll
    for (int s = 0; s < 8; ++s) {
        S0[s] = *(const float4*)(zrow + s * 32);
        S1[s] = *(const float4*)(zrow + s * 32 + 4);
    }

    for (int i = 0; i < niter; ++i) {
        const bool active = t < ntiles;
        const int tn = t + PAIRS;
        const int tnc = (tn < ntiles) ? tn : (ntiles - 1);
        const float* zrow_n = z + (size_t)(tnc * 16 + l15) * D + lg * 8;

        f32x4 acc[8];
        const f32x4 zero4 = {0.f, 0.f, 0.f, 0.f};
#pragma unroll
        for (int ct = 0; ct < 8; ++ct) acc[ct] = zero4;
        float zsq_part = 0.f;

#pragma unroll
        for (int kk = 0; kk < 8; ++kk) {
            // consume slot kk (loaded one full tile ago), refill with next tile
            float4 c0 = S0[kk], c1 = S1[kk];
            const float* pf = zrow_n + kk * 32;
            S0[kk] = *(const float4*)(pf);
            S1[kk] = *(const float4*)(pf + 4);

            zsq_part += c0.x * c0.x + c0.y * c0.y + c0.z * c0.z + c0.w * c0.w +
                        c1.x * c1.x + c1.y * c1.y + c1.z * c1.z + c1.w * c1.w;
            // packed RNE conversion: 4x v_cvt_pk_bf16_f32
            uint4 u;
            u.x = pk2(c0.x, c0.y); u.y = pk2(c0.z, c0.w);
            u.z = pk2(c1.x, c1.y); u.w = pk2(c1.z, c1.w);
            short8 af;
            __builtin_memcpy(&af, &u, 16);
#pragma unroll
            for (int ct = 0; ct < 8; ++ct) {
                // linear per-lane address -> zero bank conflicts
                short8 bf = *(const short8*)(ldsb + laneoff + ((kk * 16 + ct) << 10));
                acc[ct] = __builtin_amdgcn_mfma_f32_16x16x32_bf16(af, bf, acc[ct], 0, 0, 0);
            }
        }
        // ring now holds next tile's k-steps 0..7 (loads may still be in flight)

        // ||z_row||^2: lane holds partial for row l15; sum over the 4 lane-groups
        float zsq = zsq_part;
        zsq += __shfl_xor(zsq, 16);
        zsq += __shfl_xor(zsq, 32);
        float zsqj[4];
#pragma unroll
        for (int j = 0; j < 4; ++j) zsqj[j] = __shfl(zsq, lg * 4 + j);

        // q = rcp(max(1 + dist, 1)); per-lane partial row sums
        float rs[4] = {0.f, 0.f, 0.f, 0.f};
#pragma unroll
        for (int ct = 0; ct < 8; ++ct) {
#pragma unroll
            for (int j = 0; j < 4; ++j) {
                float d1 = zsqj[j] + csqr1[ct] - 2.0f * acc[ct][j];  // 1 + dist
                d1 = fmaxf(d1, 1.0f);                                // clamp dist >= 0
                float qv = frcp(d1);                                 // single v_rcp_f32
                acc[ct][j] = qv;
                rs[j] += qv;
            }
        }
        // reduce over the 16-lane column group -> this wave's 128-col row sums
#pragma unroll
        for (int j = 0; j < 4; ++j) {
            float s = rs[j];
            s += __shfl_xor(s, 1);
            s += __shfl_xor(s, 2);
            s += __shfl_xor(s, 4);
            s += __shfl_xor(s, 8);
            rs[j] = s;
        }
        // exchange with partner wave (other 128 cols), parity double-buffered
        if (l15 == 0) {
            float4 w = {rs[0], rs[1], rs[2], rs[3]};
            *(float4*)&ldsRS[i & 1][wave][lg * 4] = w;
        }
        asm volatile("s_waitcnt lgkmcnt(0)" ::: "memory");
        __builtin_amdgcn_s_barrier();          // raw: vmcnt NOT drained
        __builtin_amdgcn_sched_barrier(0);
        float4 prs = *(const float4*)&ldsRS[i & 1][wave ^ 1][lg * 4];
        float inv[4];
        inv[0] = frcp(rs[0] + prs.x);
        inv[1] = frcp(rs[1] + prs.y);
        inv[2] = frcp(rs[2] + prs.z);
        inv[3] = frcp(rs[3] + prs.w);

        if (active) {
#pragma unroll
            for (int j = 0; j < 4; ++j) {
                float* orow = out + (size_t)(t * 16 + lg * 4 + j) * KC + half * 128 + l15;
#pragma unroll
                for (int ct = 0; ct < 8; ++ct) {
                    // nontemporal: don't write-allocate L2/L3 (out never re-read;
                    // preserves z's L3 residency)
                    __builtin_nontemporal_store(acc[ct][j] * inv[j], &orow[ct * 16]);
                }
            }
        }
        t = tn;
        zrow = zrow_n;
    }
}

extern "C" void kernel_launch(void* const* d_in, const int* in_sizes, int n_in,
                              void* d_out, int out_size, void* d_ws, size_t ws_size,
                              hipStream_t stream) {
    const float* zp = (const float*)d_in[0];
    const float* Cp = (const float*)d_in[1];
    const int N = in_sizes[0] / D;  // 200000
    unsigned short* Bf = (unsigned short*)d_ws;                          // 128KB bf16 frag-ordered
    float* csq = (float*)((char*)d_ws + (size_t)KC * D * sizeof(unsigned short));  // 1KB

    prep_csq<<<KC, 64, 0, stream>>>(Cp, csq);
    prep_reorder<<<128, 64, 0, stream>>>(Cp, Bf);

    const int ntiles = (N + 15) / 16;  // 12500
    main_kernel<<<GRID, NT, 0, stream>>>(zp, (const uint4*)Bf, csq, (float*)d_out, ntiles);
}